// Round 2
// baseline (3545.932 us; speedup 1.0000x reference)
//
#include <hip/hip_runtime.h>
#include <hip/hip_bf16.h>

#define LRELU(x) ((x) > 0.0f ? (x) : 0.01f * (x))

typedef __attribute__((ext_vector_type(4))) short bf16x4;
typedef __attribute__((ext_vector_type(4))) float f32x4;

// Monotonic float -> uint encoding: f1 > f2  <=>  enc(f1) > enc(f2).
// enc of any finite float is > 0x007FFFFF, so 0 is a safe "empty" sentinel.
__device__ __forceinline__ unsigned fenc(float f) {
    unsigned u = __float_as_uint(f);
    return (u & 0x80000000u) ? ~u : (u | 0x80000000u);
}
__device__ __forceinline__ float fdec(unsigned u) {
    return (u & 0x80000000u) ? __uint_as_float(u & 0x7fffffffu) : __uint_as_float(~u);
}
// f32 -> bf16 (RNE) without relying on type APIs
__device__ __forceinline__ short f2bf(float f) {
    unsigned u = __float_as_uint(f);
    unsigned r = (u + 0x7FFFu + ((u >> 16) & 1u)) >> 16;
    return (short)r;
}
__device__ __forceinline__ float bf2f(short s) {
    return __uint_as_float(((unsigned)(unsigned short)s) << 16);
}

__device__ __forceinline__ f32x4 mfma16(bf16x4 a, bf16x4 b, f32x4 c) {
#if __has_builtin(__builtin_amdgcn_mfma_f32_16x16x16bf16_1k)
    return __builtin_amdgcn_mfma_f32_16x16x16bf16_1k(a, b, c, 0, 0, 0);
#else
    asm("v_mfma_f32_16x16x16_bf16 %0, %1, %2, %0" : "+v"(c) : "v"(a), "v"(b));
    return c;
#endif
}

// ---------------------------------------------------------------------------
// Edge embedding MLP via MFMA, fully in-register.
//   Per wave, 16 edges at a time. We compute Y^T = W^T (x) act for each layer:
//   mfma(A=W^T frag, B=act frag) -> D: col(lane&15)=edge, row=channel.
//   K=16 D layout row=(l>>4)*4+j == next layer's B-frag k=(l>>4)*4+j, so each
//   layer's accumulator re-packs per-lane (f32->bf16) into the next B operand.
//   Output stored in fragment-native layout:
//     ea[eb*1024 + t*256 + lane*4 + j] = Y[eb*16 + (lane&15)][t*16+(lane>>4)*4+j]
// ---------------------------------------------------------------------------
__global__ __launch_bounds__(256) void edge_mlp_mfma(
    const float* __restrict__ eattr,
    const float* __restrict__ W1, const float* __restrict__ b1,
    const float* __restrict__ W2, const float* __restrict__ b2,
    const float* __restrict__ W3, const float* __restrict__ b3,
    __hip_bfloat16* __restrict__ eout, int E)
{
    const int lane = threadIdx.x & 63;
    const int el   = lane & 15;   // edge slot
    const int g    = lane >> 4;   // lane group

    // ---- stationary weight/bias fragments (registers, static indexing) ----
    bf16x4 w1f[4];            // [t]  (K padded 8->16; groups 2,3 zero)
    bf16x4 w2f[4][4];         // [t][kb]
    bf16x4 w3f[4][4];
    f32x4  bf1[4], bf2[4], bf3[4];
#pragma unroll
    for (int t = 0; t < 4; ++t) {
        const int c = t * 16 + el;
#pragma unroll
        for (int j = 0; j < 4; ++j) {
            const int k = g * 4 + j;
            w1f[t][j] = (k < 8) ? f2bf(W1[k * 64 + c]) : (short)0;
        }
#pragma unroll
        for (int kb = 0; kb < 4; ++kb) {
#pragma unroll
            for (int j = 0; j < 4; ++j) {
                const int k = kb * 16 + g * 4 + j;
                w2f[t][kb][j] = f2bf(W2[k * 64 + c]);
                w3f[t][kb][j] = f2bf(W3[k * 64 + c]);
            }
        }
        const float4 v1 = *reinterpret_cast<const float4*>(b1 + t * 16 + g * 4);
        const float4 v2 = *reinterpret_cast<const float4*>(b2 + t * 16 + g * 4);
        const float4 v3 = *reinterpret_cast<const float4*>(b3 + t * 16 + g * 4);
        bf1[t][0] = v1.x; bf1[t][1] = v1.y; bf1[t][2] = v1.z; bf1[t][3] = v1.w;
        bf2[t][0] = v2.x; bf2[t][1] = v2.y; bf2[t][2] = v2.z; bf2[t][3] = v2.w;
        bf3[t][0] = v3.x; bf3[t][1] = v3.y; bf3[t][2] = v3.z; bf3[t][3] = v3.w;
    }

    const int nblk = (E + 15) >> 4;
    const int wid  = (int)((blockIdx.x * blockDim.x + threadIdx.x) >> 6);
    const int nw   = (int)((gridDim.x * blockDim.x) >> 6);

    for (int eb = wid; eb < nblk; eb += nw) {
        const int e  = eb * 16 + el;
        const int ec = min(e, E - 1);

        // B1 fragment: edge attrs (K=8 real, rest zero)
        bf16x4 bfr = (bf16x4)0;
        if (g < 2) {
            const float4 av = *reinterpret_cast<const float4*>(eattr + (size_t)ec * 8 + g * 4);
            bfr[0] = f2bf(av.x); bfr[1] = f2bf(av.y);
            bfr[2] = f2bf(av.z); bfr[3] = f2bf(av.w);
        }

        f32x4  acc[4];
        bf16x4 act[4];

        // layer 1 (one K=16 mfma per 16-channel tile), bias as acc init
#pragma unroll
        for (int t = 0; t < 4; ++t) acc[t] = mfma16(w1f[t], bfr, bf1[t]);
#pragma unroll
        for (int t = 0; t < 4; ++t)
#pragma unroll
            for (int j = 0; j < 4; ++j) act[t][j] = f2bf(fmaxf(acc[t][j], 0.0f));

        // layer 2
#pragma unroll
        for (int t = 0; t < 4; ++t) {
            f32x4 a = bf2[t];
#pragma unroll
            for (int kb = 0; kb < 4; ++kb) a = mfma16(w2f[t][kb], act[kb], a);
            acc[t] = a;
        }
#pragma unroll
        for (int t = 0; t < 4; ++t)
#pragma unroll
            for (int j = 0; j < 4; ++j) act[t][j] = f2bf(fmaxf(acc[t][j], 0.0f));

        // layer 3 + fragment-native store
#pragma unroll
        for (int t = 0; t < 4; ++t) {
            f32x4 a = bf3[t];
#pragma unroll
            for (int kb = 0; kb < 4; ++kb) a = mfma16(w3f[t][kb], act[kb], a);
            bf16x4 o;
#pragma unroll
            for (int j = 0; j < 4; ++j) o[j] = f2bf(a[j]);
            if (e < E) {
                *reinterpret_cast<bf16x4*>(
                    reinterpret_cast<short*>(eout) + (size_t)eb * 1024 + t * 256 + lane * 4) = o;
            }
        }
    }
}

// ---------------------------------------------------------------------------
// Node embedding MLP: h = L3(relu(L2(relu(L1(x)))))   x:[N,4] -> h:[N,64]
// Weight-stationary VALU (small: N=100k). 4 partial accumulators break the
// serial FMA chain (64 -> 16 dep length).
// ---------------------------------------------------------------------------
__global__ __launch_bounds__(256) void node_mlp_kernel(
    const float* __restrict__ x,
    const float* __restrict__ W1, const float* __restrict__ b1,
    const float* __restrict__ W2, const float* __restrict__ b2,
    const float* __restrict__ W3, const float* __restrict__ b3,
    float* __restrict__ h, int N)
{
    __shared__ __align__(16) float smem[4 * 64];
    const int lane = threadIdx.x & 63;
    const int wid  = threadIdx.x >> 6;

    float w1c[4], w2c[64], w3c[64];
#pragma unroll
    for (int i = 0; i < 4; ++i)  w1c[i] = W1[i * 64 + lane];
#pragma unroll
    for (int k = 0; k < 64; ++k) w2c[k] = W2[k * 64 + lane];
#pragma unroll
    for (int k = 0; k < 64; ++k) w3c[k] = W3[k * 64 + lane];
    const float bb1 = b1[lane], bb2 = b2[lane], bb3 = b3[lane];

    const int nwave = gridDim.x * 4;
    const int w     = blockIdx.x * 4 + wid;
    const int chunk = (N + nwave - 1) / nwave;
    const int n0 = w * chunk;
    const int n1 = min(N, n0 + chunk);
    float* myrow = &smem[wid * 64];

    for (int n = n0; n < n1; ++n) {
        const float4 xv = *reinterpret_cast<const float4*>(x + (size_t)n * 4);
        float a1 = bb1 + xv.x * w1c[0] + xv.y * w1c[1] + xv.z * w1c[2] + xv.w * w1c[3];
        a1 = fmaxf(a1, 0.0f);
        myrow[lane] = a1;
        asm volatile("s_waitcnt lgkmcnt(0)" ::: "memory");
        float s0 = 0.f, s1 = 0.f, s2 = 0.f, s3 = 0.f;
#pragma unroll
        for (int k4 = 0; k4 < 16; ++k4) {
            const float4 hv = *reinterpret_cast<const float4*>(&myrow[k4 * 4]);
            s0 += hv.x * w2c[k4 * 4];     s1 += hv.y * w2c[k4 * 4 + 1];
            s2 += hv.z * w2c[k4 * 4 + 2]; s3 += hv.w * w2c[k4 * 4 + 3];
        }
        float a2 = fmaxf(bb2 + ((s0 + s1) + (s2 + s3)), 0.0f);
        asm volatile("s_waitcnt lgkmcnt(0)" ::: "memory");
        myrow[lane] = a2;
        asm volatile("s_waitcnt lgkmcnt(0)" ::: "memory");
        s0 = 0.f; s1 = 0.f; s2 = 0.f; s3 = 0.f;
#pragma unroll
        for (int k4 = 0; k4 < 16; ++k4) {
            const float4 hv = *reinterpret_cast<const float4*>(&myrow[k4 * 4]);
            s0 += hv.x * w3c[k4 * 4];     s1 += hv.y * w3c[k4 * 4 + 1];
            s2 += hv.z * w3c[k4 * 4 + 2]; s3 += hv.w * w3c[k4 * 4 + 3];
        }
        h[(size_t)n * 64 + lane] = bb3 + ((s0 + s1) + (s2 + s3));
    }
}

// ---------------------------------------------------------------------------
// Message + segment_max over dst. Consumes ea in fragment layout:
// lane holds edge (lane&15), channels t*16 + (lane>>4)*4 + {0..3}.
// ---------------------------------------------------------------------------
__global__ __launch_bounds__(256) void msg_kernel(
    const int* __restrict__ ei,            // [2, E]
    const __hip_bfloat16* __restrict__ ea, // fragment layout
    const float* __restrict__ h,           // [N, 64]
    unsigned* __restrict__ agg,            // [N, 64] encoded
    int E)
{
    const int lane = threadIdx.x & 63;
    const int el   = lane & 15;
    const int g    = lane >> 4;
    const int nblk = (E + 15) >> 4;
    const int wid  = (int)((blockIdx.x * blockDim.x + threadIdx.x) >> 6);
    const int nw   = (int)((gridDim.x * blockDim.x) >> 6);

    for (int eb = wid; eb < nblk; eb += nw) {
        const int e = eb * 16 + el;
        const bool valid = (e < E);
        const int ec = valid ? e : 0;
        const int s = ei[ec];
        const int d = ei[E + ec];
        const float* hp = h + (size_t)s * 64 + g * 4;
        unsigned*    ap = agg + (size_t)d * 64 + g * 4;
        const short* eap = reinterpret_cast<const short*>(ea) + (size_t)eb * 1024 + lane * 4;
#pragma unroll
        for (int t = 0; t < 4; ++t) {
            const bf16x4 ev = *reinterpret_cast<const bf16x4*>(eap + t * 256);
            const float4 hv = *reinterpret_cast<const float4*>(hp + t * 16);
            float m0 = hv.x + bf2f(ev[0]);
            float m1 = hv.y + bf2f(ev[1]);
            float m2 = hv.z + bf2f(ev[2]);
            float m3 = hv.w + bf2f(ev[3]);
            m0 = LRELU(m0); m1 = LRELU(m1); m2 = LRELU(m2); m3 = LRELU(m3);
            if (valid) {
                atomicMax(ap + t * 16 + 0, fenc(m0));
                atomicMax(ap + t * 16 + 1, fenc(m1));
                atomicMax(ap + t * 16 + 2, fenc(m2));
                atomicMax(ap + t * 16 + 3, fenc(m3));
            }
        }
    }
}

// ---------------------------------------------------------------------------
// GINE node update + graph pooling (batch sorted -> running max per wave).
// ---------------------------------------------------------------------------
__global__ __launch_bounds__(256) void node_update_kernel(
    float* __restrict__ h,
    const unsigned* __restrict__ agg,
    const int* __restrict__ batch,
    const float* __restrict__ geps,
    const float* __restrict__ gW1, const float* __restrict__ gb1,
    const float* __restrict__ gW2, const float* __restrict__ gb2,
    unsigned* __restrict__ pooled,  // [128, 192] encoded
    int l, int N)
{
    __shared__ __align__(16) float smem[4 * 64];
    const int lane = threadIdx.x & 63;
    const int wid  = threadIdx.x >> 6;

    const float* W1 = gW1 + (size_t)l * 4096;
    const float* W2 = gW2 + (size_t)l * 4096;
    float w1c[64], w2c[64];
#pragma unroll
    for (int k = 0; k < 64; ++k) w1c[k] = W1[k * 64 + lane];
#pragma unroll
    for (int k = 0; k < 64; ++k) w2c[k] = W2[k * 64 + lane];
    const float bb1 = gb1[l * 64 + lane], bb2 = gb2[l * 64 + lane];
    const float ope = 1.0f + geps[l];

    const int nwave = gridDim.x * 4;
    const int w     = blockIdx.x * 4 + wid;
    const int chunk = (N + nwave - 1) / nwave;
    const int n0 = w * chunk;
    const int n1 = min(N, n0 + chunk);
    float* myrow = &smem[wid * 64];

    int curg = -1;
    float vmax = 0.0f;
    for (int n = n0; n < n1; ++n) {
        const float hv = h[(size_t)n * 64 + lane];
        const unsigned au = agg[(size_t)n * 64 + lane];
        const float av = (au == 0u) ? 0.0f : fdec(au);
        const float z = ope * hv + av;
        myrow[lane] = z;
        asm volatile("s_waitcnt lgkmcnt(0)" ::: "memory");
        float s0 = 0.f, s1 = 0.f, s2 = 0.f, s3 = 0.f;
#pragma unroll
        for (int k4 = 0; k4 < 16; ++k4) {
            const float4 zv = *reinterpret_cast<const float4*>(&myrow[k4 * 4]);
            s0 += zv.x * w1c[k4 * 4];     s1 += zv.y * w1c[k4 * 4 + 1];
            s2 += zv.z * w1c[k4 * 4 + 2]; s3 += zv.w * w1c[k4 * 4 + 3];
        }
        float t = bb1 + ((s0 + s1) + (s2 + s3));
        t = LRELU(t);
        asm volatile("s_waitcnt lgkmcnt(0)" ::: "memory");
        myrow[lane] = t;
        asm volatile("s_waitcnt lgkmcnt(0)" ::: "memory");
        s0 = 0.f; s1 = 0.f; s2 = 0.f; s3 = 0.f;
#pragma unroll
        for (int k4 = 0; k4 < 16; ++k4) {
            const float4 tv = *reinterpret_cast<const float4*>(&myrow[k4 * 4]);
            s0 += tv.x * w2c[k4 * 4];     s1 += tv.y * w2c[k4 * 4 + 1];
            s2 += tv.z * w2c[k4 * 4 + 2]; s3 += tv.w * w2c[k4 * 4 + 3];
        }
        const float o = bb2 + ((s0 + s1) + (s2 + s3));
        h[(size_t)n * 64 + lane] = o;

        const int g = batch[n];  // sorted, wave-uniform
        if (g != curg) {
            if (curg >= 0)
                atomicMax(&pooled[curg * 192 + l * 64 + lane], fenc(vmax));
            curg = g;
            vmax = o;
        } else {
            vmax = fmaxf(vmax, o);
        }
    }
    if (curg >= 0)
        atomicMax(&pooled[curg * 192 + l * 64 + lane], fenc(vmax));
}

// ---------------------------------------------------------------------------
// Output head: per graph  y=leaky(gamma*(hp@oW1+ob1)+beta); logit=y@oW2+ob2
// out[0..127] = logits, out[128..255] = sigmoid(logits)
// ---------------------------------------------------------------------------
__global__ __launch_bounds__(192) void out_kernel(
    const unsigned* __restrict__ pooled,
    const float* __restrict__ oW1, const float* __restrict__ ob1,
    const float* __restrict__ ogamma, const float* __restrict__ obeta,
    const float* __restrict__ oW2, const float* __restrict__ ob2,
    float* __restrict__ out)
{
    __shared__ float hp[192];
    __shared__ float partial[3];
    const int c = threadIdx.x;
    const int g = blockIdx.x;

    const unsigned u = pooled[g * 192 + c];
    hp[c] = (u == 0u) ? -INFINITY : fdec(u);
    __syncthreads();

    float y = ob1[c];
#pragma unroll 4
    for (int k = 0; k < 192; ++k)
        y += hp[k] * oW1[k * 192 + c];
    y = ogamma[c] * y + obeta[c];
    y = LRELU(y);
    float contrib = y * oW2[c];

#pragma unroll
    for (int off = 32; off > 0; off >>= 1)
        contrib += __shfl_xor(contrib, off);
    if ((threadIdx.x & 63) == 0) partial[threadIdx.x >> 6] = contrib;
    __syncthreads();
    if (threadIdx.x == 0) {
        const float logit = partial[0] + partial[1] + partial[2] + ob2[0];
        out[g] = logit;
        out[128 + g] = 1.0f / (1.0f + expf(-logit));
    }
}

extern "C" void kernel_launch(void* const* d_in, const int* in_sizes, int n_in,
                              void* d_out, int out_size, void* d_ws, size_t ws_size,
                              hipStream_t stream)
{
    const float* x     = (const float*)d_in[0];
    const int*   ei    = (const int*)d_in[1];
    const int*   batch = (const int*)d_in[2];
    const float* eattr = (const float*)d_in[3];
    const float* nW1 = (const float*)d_in[4],  *nb1 = (const float*)d_in[5];
    const float* nW2 = (const float*)d_in[6],  *nb2 = (const float*)d_in[7];
    const float* nW3 = (const float*)d_in[8],  *nb3 = (const float*)d_in[9];
    const float* eW1 = (const float*)d_in[10], *eb1 = (const float*)d_in[11];
    const float* eW2 = (const float*)d_in[12], *eb2 = (const float*)d_in[13];
    const float* eW3 = (const float*)d_in[14], *eb3 = (const float*)d_in[15];
    const float* geps = (const float*)d_in[16];
    const float* gW1 = (const float*)d_in[17], *gb1 = (const float*)d_in[18];
    const float* gW2 = (const float*)d_in[19], *gb2 = (const float*)d_in[20];
    const float* oW1 = (const float*)d_in[21], *ob1 = (const float*)d_in[22];
    const float* ogamma = (const float*)d_in[23], *obeta = (const float*)d_in[24];
    const float* oW2 = (const float*)d_in[25], *ob2 = (const float*)d_in[26];
    float* out = (float*)d_out;

    const int N = in_sizes[0] / 4;   // 100000
    const int E = in_sizes[3] / 8;   // 1600000

    // workspace layout (all offsets 256B-aligned)
    char* ws = (char*)d_ws;
    const size_t ea_bytes  = (((size_t)E + 15) & ~(size_t)15) * 64 * sizeof(__hip_bfloat16);
    const size_t h_bytes   = (size_t)N * 64 * sizeof(float);
    const size_t agg_bytes = (size_t)N * 64 * sizeof(unsigned);
    __hip_bfloat16* ea  = (__hip_bfloat16*)ws;
    float*    h      = (float*)(ws + ea_bytes);
    unsigned* agg    = (unsigned*)(ws + ea_bytes + h_bytes);
    unsigned* pooled = (unsigned*)(ws + ea_bytes + h_bytes + agg_bytes);
    (void)ws_size;

    hipMemsetAsync(pooled, 0, 128 * 192 * sizeof(unsigned), stream);

    node_mlp_kernel<<<512, 256, 0, stream>>>(x, nW1, nb1, nW2, nb2, nW3, nb3, h, N);
    edge_mlp_mfma<<<1024, 256, 0, stream>>>(eattr, eW1, eb1, eW2, eb2, eW3, eb3, ea, E);

    for (int l = 0; l < 3; ++l) {
        hipMemsetAsync(agg, 0, agg_bytes, stream);
        msg_kernel<<<4096, 256, 0, stream>>>(ei, ea, h, agg, E);
        node_update_kernel<<<512, 256, 0, stream>>>(h, agg, batch, geps,
                                                    gW1, gb1, gW2, gb2, pooled, l, N);
    }

    out_kernel<<<128, 192, 0, stream>>>(pooled, oW1, ob1, ogamma, obeta, oW2, ob2, out);
}

// Round 3
// 1161.171 us; speedup vs baseline: 3.0538x; 3.0538x over previous
//
#include <hip/hip_runtime.h>
#include <hip/hip_bf16.h>

#define LRELU(x) ((x) > 0.0f ? (x) : 0.01f * (x))

typedef __attribute__((ext_vector_type(4))) short bf16x4;
typedef __attribute__((ext_vector_type(4))) float f32x4;

// Monotonic float -> uint encoding for max-atomics on pooled.
__device__ __forceinline__ unsigned fenc(float f) {
    unsigned u = __float_as_uint(f);
    return (u & 0x80000000u) ? ~u : (u | 0x80000000u);
}
__device__ __forceinline__ float fdec(unsigned u) {
    return (u & 0x80000000u) ? __uint_as_float(u & 0x7fffffffu) : __uint_as_float(~u);
}
__device__ __forceinline__ short f2bf(float f) {
    unsigned u = __float_as_uint(f);
    unsigned r = (u + 0x7FFFu + ((u >> 16) & 1u)) >> 16;
    return (short)r;
}
__device__ __forceinline__ float bf2f(short s) {
    return __uint_as_float(((unsigned)(unsigned short)s) << 16);
}

__device__ __forceinline__ f32x4 mfma16(bf16x4 a, bf16x4 b, f32x4 c) {
#if __has_builtin(__builtin_amdgcn_mfma_f32_16x16x16bf16_1k)
    return __builtin_amdgcn_mfma_f32_16x16x16bf16_1k(a, b, c, 0, 0, 0);
#else
    asm("v_mfma_f32_16x16x16_bf16 %0, %1, %2, %0" : "+v"(c) : "v"(a), "v"(b));
    return c;
#endif
}

// ---------------------------------------------------------------------------
// CSR build step 1: histogram of dst
// ---------------------------------------------------------------------------
__global__ __launch_bounds__(256) void hist_kernel(const int* __restrict__ ei,
                                                   int* __restrict__ deg, int E)
{
    const int stride = gridDim.x * blockDim.x;
    for (int e = blockIdx.x * blockDim.x + threadIdx.x; e < E; e += stride)
        atomicAdd(&deg[ei[E + e]], 1);
}

// ---------------------------------------------------------------------------
// CSR build step 2: single-block exclusive scan deg -> rowptr (+cursor copy)
// ---------------------------------------------------------------------------
__global__ __launch_bounds__(1024) void scan_kernel(const int* __restrict__ deg,
                                                    int* __restrict__ rowptr,
                                                    int* __restrict__ cursor, int N)
{
    __shared__ int wsum[16];
    __shared__ int tiletot;
    const int lane = threadIdx.x & 63;
    const int w    = threadIdx.x >> 6;
    int carry = 0;
    for (int base = 0; base < N; base += 1024) {
        const int i = base + (int)threadIdx.x;
        const int v = (i < N) ? deg[i] : 0;
        int s = v;
#pragma unroll
        for (int off = 1; off < 64; off <<= 1) {
            int t = __shfl_up(s, off);
            if (lane >= off) s += t;
        }
        if (lane == 63) wsum[w] = s;
        __syncthreads();
        if (threadIdx.x == 0) {
            int acc = 0;
#pragma unroll
            for (int k = 0; k < 16; ++k) { int t = wsum[k]; wsum[k] = acc; acc += t; }
            tiletot = acc;
        }
        __syncthreads();
        const int excl = carry + wsum[w] + (s - v);
        if (i < N) { rowptr[i] = excl; cursor[i] = excl; }
        carry += tiletot;
        __syncthreads();
    }
    if (threadIdx.x == 0) rowptr[N] = carry;
}

// ---------------------------------------------------------------------------
// Edge embedding MLP via MFMA (in-register), fused with CSR scatter:
// each edge's output row (64ch bf16) is written to its dst-sorted position,
// and srcs_sorted[pos] = src. Aggregation then streams ea sequentially.
// D-frag: col(lane&15)=edge, row ch = t*16 + (lane>>4)*4 + j.
// ---------------------------------------------------------------------------
__global__ __launch_bounds__(256) void edge_mlp_mfma(
    const float* __restrict__ eattr,
    const float* __restrict__ W1, const float* __restrict__ b1,
    const float* __restrict__ W2, const float* __restrict__ b2,
    const float* __restrict__ W3, const float* __restrict__ b3,
    const int* __restrict__ ei, int* __restrict__ cursor,
    int* __restrict__ srcs_sorted,
    __hip_bfloat16* __restrict__ eout, int E)
{
    const int lane = threadIdx.x & 63;
    const int el   = lane & 15;   // edge slot
    const int g    = lane >> 4;   // lane group

    bf16x4 w1f[4];
    bf16x4 w2f[4][4];
    bf16x4 w3f[4][4];
    f32x4  bf1[4], bf2[4], bf3[4];
#pragma unroll
    for (int t = 0; t < 4; ++t) {
        const int c = t * 16 + el;
#pragma unroll
        for (int j = 0; j < 4; ++j) {
            const int k = g * 4 + j;
            w1f[t][j] = (k < 8) ? f2bf(W1[k * 64 + c]) : (short)0;
        }
#pragma unroll
        for (int kb = 0; kb < 4; ++kb) {
#pragma unroll
            for (int j = 0; j < 4; ++j) {
                const int k = kb * 16 + g * 4 + j;
                w2f[t][kb][j] = f2bf(W2[k * 64 + c]);
                w3f[t][kb][j] = f2bf(W3[k * 64 + c]);
            }
        }
        const float4 v1 = *reinterpret_cast<const float4*>(b1 + t * 16 + g * 4);
        const float4 v2 = *reinterpret_cast<const float4*>(b2 + t * 16 + g * 4);
        const float4 v3 = *reinterpret_cast<const float4*>(b3 + t * 16 + g * 4);
        bf1[t][0] = v1.x; bf1[t][1] = v1.y; bf1[t][2] = v1.z; bf1[t][3] = v1.w;
        bf2[t][0] = v2.x; bf2[t][1] = v2.y; bf2[t][2] = v2.z; bf2[t][3] = v2.w;
        bf3[t][0] = v3.x; bf3[t][1] = v3.y; bf3[t][2] = v3.z; bf3[t][3] = v3.w;
    }

    const int nblk = (E + 15) >> 4;
    const int wid  = (int)((blockIdx.x * blockDim.x + threadIdx.x) >> 6);
    const int nw   = (int)((gridDim.x * blockDim.x) >> 6);

    for (int eb = wid; eb < nblk; eb += nw) {
        const int e  = eb * 16 + el;
        const int ec = min(e, E - 1);

        // sorted position for this block's 16 edges (lanes 0..15 do the work)
        int p = 0;
        if (lane < 16) {
            const int eL = eb * 16 + lane;
            if (eL < E) {
                const int d = ei[E + eL];
                p = atomicAdd(&cursor[d], 1);
                srcs_sorted[p] = ei[eL];
            }
        }
        const int pd = __shfl(p, el);

        // B1 fragment: edge attrs (K=8 real, rest zero)
        bf16x4 bfr = (bf16x4)0;
        if (g < 2) {
            const float4 av = *reinterpret_cast<const float4*>(eattr + (size_t)ec * 8 + g * 4);
            bfr[0] = f2bf(av.x); bfr[1] = f2bf(av.y);
            bfr[2] = f2bf(av.z); bfr[3] = f2bf(av.w);
        }

        f32x4  acc[4];
        bf16x4 act[4];

#pragma unroll
        for (int t = 0; t < 4; ++t) acc[t] = mfma16(w1f[t], bfr, bf1[t]);
#pragma unroll
        for (int t = 0; t < 4; ++t)
#pragma unroll
            for (int j = 0; j < 4; ++j) act[t][j] = f2bf(fmaxf(acc[t][j], 0.0f));

#pragma unroll
        for (int t = 0; t < 4; ++t) {
            f32x4 a = bf2[t];
#pragma unroll
            for (int kb = 0; kb < 4; ++kb) a = mfma16(w2f[t][kb], act[kb], a);
            acc[t] = a;
        }
#pragma unroll
        for (int t = 0; t < 4; ++t)
#pragma unroll
            for (int j = 0; j < 4; ++j) act[t][j] = f2bf(fmaxf(acc[t][j], 0.0f));

#pragma unroll
        for (int t = 0; t < 4; ++t) {
            f32x4 a = bf3[t];
#pragma unroll
            for (int kb = 0; kb < 4; ++kb) a = mfma16(w3f[t][kb], act[kb], a);
            bf16x4 o;
#pragma unroll
            for (int j = 0; j < 4; ++j) o[j] = f2bf(a[j]);
            if (e < E) {
                // row-major store into dst-sorted row pd: ch = t*16 + g*4 .. +3
                *reinterpret_cast<bf16x4*>(
                    reinterpret_cast<short*>(eout) + (size_t)pd * 64 + t * 16 + g * 4) = o;
            }
        }
    }
}

// ---------------------------------------------------------------------------
// Node embedding MLP: x:[N,4] -> h:[N,64] (weight-stationary VALU)
// ---------------------------------------------------------------------------
__global__ __launch_bounds__(256) void node_mlp_kernel(
    const float* __restrict__ x,
    const float* __restrict__ W1, const float* __restrict__ b1,
    const float* __restrict__ W2, const float* __restrict__ b2,
    const float* __restrict__ W3, const float* __restrict__ b3,
    float* __restrict__ h, int N)
{
    __shared__ __align__(16) float smem[4 * 64];
    const int lane = threadIdx.x & 63;
    const int wid  = threadIdx.x >> 6;

    float w1c[4], w2c[64], w3c[64];
#pragma unroll
    for (int i = 0; i < 4; ++i)  w1c[i] = W1[i * 64 + lane];
#pragma unroll
    for (int k = 0; k < 64; ++k) w2c[k] = W2[k * 64 + lane];
#pragma unroll
    for (int k = 0; k < 64; ++k) w3c[k] = W3[k * 64 + lane];
    const float bb1 = b1[lane], bb2 = b2[lane], bb3 = b3[lane];

    const int nwave = gridDim.x * 4;
    const int w     = blockIdx.x * 4 + wid;
    const int chunk = (N + nwave - 1) / nwave;
    const int n0 = w * chunk;
    const int n1 = min(N, n0 + chunk);
    float* myrow = &smem[wid * 64];

    for (int n = n0; n < n1; ++n) {
        const float4 xv = *reinterpret_cast<const float4*>(x + (size_t)n * 4);
        float a1 = bb1 + xv.x * w1c[0] + xv.y * w1c[1] + xv.z * w1c[2] + xv.w * w1c[3];
        a1 = fmaxf(a1, 0.0f);
        myrow[lane] = a1;
        asm volatile("s_waitcnt lgkmcnt(0)" ::: "memory");
        float s0 = 0.f, s1 = 0.f, s2 = 0.f, s3 = 0.f;
#pragma unroll
        for (int k4 = 0; k4 < 16; ++k4) {
            const float4 hv = *reinterpret_cast<const float4*>(&myrow[k4 * 4]);
            s0 += hv.x * w2c[k4 * 4];     s1 += hv.y * w2c[k4 * 4 + 1];
            s2 += hv.z * w2c[k4 * 4 + 2]; s3 += hv.w * w2c[k4 * 4 + 3];
        }
        float a2 = fmaxf(bb2 + ((s0 + s1) + (s2 + s3)), 0.0f);
        asm volatile("s_waitcnt lgkmcnt(0)" ::: "memory");
        myrow[lane] = a2;
        asm volatile("s_waitcnt lgkmcnt(0)" ::: "memory");
        s0 = 0.f; s1 = 0.f; s2 = 0.f; s3 = 0.f;
#pragma unroll
        for (int k4 = 0; k4 < 16; ++k4) {
            const float4 hv = *reinterpret_cast<const float4*>(&myrow[k4 * 4]);
            s0 += hv.x * w3c[k4 * 4];     s1 += hv.y * w3c[k4 * 4 + 1];
            s2 += hv.z * w3c[k4 * 4 + 2]; s3 += hv.w * w3c[k4 * 4 + 3];
        }
        h[(size_t)n * 64 + lane] = bb3 + ((s0 + s1) + (s2 + s3));
    }
}

// ---------------------------------------------------------------------------
// Fused GINE layer: CSR max-aggregation (no atomics) + node MLP + pooling.
// Wave processes contiguous nodes. Aggregation: 4 edges in flight
// (g=lane>>4 selects edge, el=lane&15 selects 4-channel group).
// ---------------------------------------------------------------------------
__global__ __launch_bounds__(256) void gine_layer(
    const float* __restrict__ h_in, float* __restrict__ h_out,
    const int* __restrict__ rowptr, const int* __restrict__ srcs,
    const __hip_bfloat16* __restrict__ eas,
    const int* __restrict__ batch, const float* __restrict__ geps,
    const float* __restrict__ gW1, const float* __restrict__ gb1,
    const float* __restrict__ gW2, const float* __restrict__ gb2,
    unsigned* __restrict__ pooled, int l, int N)
{
    __shared__ __align__(16) float smem[4 * 64];
    const int lane = threadIdx.x & 63;
    const int wid  = threadIdx.x >> 6;
    const int g    = lane >> 4;
    const int el   = lane & 15;

    const float* W1 = gW1 + (size_t)l * 4096;
    const float* W2 = gW2 + (size_t)l * 4096;
    float w1c[64], w2c[64];
#pragma unroll
    for (int k = 0; k < 64; ++k) w1c[k] = W1[k * 64 + lane];
#pragma unroll
    for (int k = 0; k < 64; ++k) w2c[k] = W2[k * 64 + lane];
    const float bb1 = gb1[l * 64 + lane], bb2 = gb2[l * 64 + lane];
    const float ope = 1.0f + geps[l];

    const int nwave = gridDim.x * 4;
    const int w     = blockIdx.x * 4 + wid;
    const int chunk = (N + nwave - 1) / nwave;
    const int n0 = w * chunk;
    const int n1 = min(N, n0 + chunk);
    float* myrow = &smem[wid * 64];
    const short* eap = reinterpret_cast<const short*>(eas);

    int curg = -1;
    float vmax = 0.0f;
    for (int n = n0; n < n1; ++n) {
        const int r0 = rowptr[n], r1 = rowptr[n + 1];

        float m0 = -INFINITY, m1 = -INFINITY, m2 = -INFINITY, m3 = -INFINITY;
        for (int r = r0; r < r1; r += 4) {
            const int re  = r + g;
            const bool vl = (re < r1);
            const int rc  = vl ? re : r0;
            const int s   = srcs[rc];
            const float4 hv = *reinterpret_cast<const float4*>(h_in + (size_t)s * 64 + el * 4);
            const bf16x4 ev = *reinterpret_cast<const bf16x4*>(eap + (size_t)rc * 64 + el * 4);
            float c0 = hv.x + bf2f(ev[0]);
            float c1 = hv.y + bf2f(ev[1]);
            float c2 = hv.z + bf2f(ev[2]);
            float c3 = hv.w + bf2f(ev[3]);
            c0 = LRELU(c0); c1 = LRELU(c1); c2 = LRELU(c2); c3 = LRELU(c3);
            if (vl) {
                m0 = fmaxf(m0, c0); m1 = fmaxf(m1, c1);
                m2 = fmaxf(m2, c2); m3 = fmaxf(m3, c3);
            }
        }
        // combine the 4 edge-groups (lanes el, el+16, el+32, el+48)
        m0 = fmaxf(m0, __shfl_xor(m0, 16)); m0 = fmaxf(m0, __shfl_xor(m0, 32));
        m1 = fmaxf(m1, __shfl_xor(m1, 16)); m1 = fmaxf(m1, __shfl_xor(m1, 32));
        m2 = fmaxf(m2, __shfl_xor(m2, 16)); m2 = fmaxf(m2, __shfl_xor(m2, 32));
        m3 = fmaxf(m3, __shfl_xor(m3, 16)); m3 = fmaxf(m3, __shfl_xor(m3, 32));

        const float4 hn = *reinterpret_cast<const float4*>(h_in + (size_t)n * 64 + el * 4);
        float4 z;
        z.x = ope * hn.x + ((m0 == -INFINITY) ? 0.0f : m0);
        z.y = ope * hn.y + ((m1 == -INFINITY) ? 0.0f : m1);
        z.z = ope * hn.z + ((m2 == -INFINITY) ? 0.0f : m2);
        z.w = ope * hn.w + ((m3 == -INFINITY) ? 0.0f : m3);
        if (g == 0) *reinterpret_cast<float4*>(&myrow[el * 4]) = z;
        asm volatile("s_waitcnt lgkmcnt(0)" ::: "memory");

        float s0 = 0.f, s1 = 0.f, s2 = 0.f, s3 = 0.f;
#pragma unroll
        for (int k4 = 0; k4 < 16; ++k4) {
            const float4 zv = *reinterpret_cast<const float4*>(&myrow[k4 * 4]);
            s0 += zv.x * w1c[k4 * 4];     s1 += zv.y * w1c[k4 * 4 + 1];
            s2 += zv.z * w1c[k4 * 4 + 2]; s3 += zv.w * w1c[k4 * 4 + 3];
        }
        float t = bb1 + ((s0 + s1) + (s2 + s3));
        t = LRELU(t);
        asm volatile("s_waitcnt lgkmcnt(0)" ::: "memory");
        myrow[lane] = t;
        asm volatile("s_waitcnt lgkmcnt(0)" ::: "memory");
        s0 = 0.f; s1 = 0.f; s2 = 0.f; s3 = 0.f;
#pragma unroll
        for (int k4 = 0; k4 < 16; ++k4) {
            const float4 tv = *reinterpret_cast<const float4*>(&myrow[k4 * 4]);
            s0 += tv.x * w2c[k4 * 4];     s1 += tv.y * w2c[k4 * 4 + 1];
            s2 += tv.z * w2c[k4 * 4 + 2]; s3 += tv.w * w2c[k4 * 4 + 3];
        }
        const float o = bb2 + ((s0 + s1) + (s2 + s3));
        h_out[(size_t)n * 64 + lane] = o;

        const int gb = batch[n];  // sorted, wave-uniform
        if (gb != curg) {
            if (curg >= 0)
                atomicMax(&pooled[curg * 192 + l * 64 + lane], fenc(vmax));
            curg = gb;
            vmax = o;
        } else {
            vmax = fmaxf(vmax, o);
        }
    }
    if (curg >= 0)
        atomicMax(&pooled[curg * 192 + l * 64 + lane], fenc(vmax));
}

// ---------------------------------------------------------------------------
// Output head
// ---------------------------------------------------------------------------
__global__ __launch_bounds__(192) void out_kernel(
    const unsigned* __restrict__ pooled,
    const float* __restrict__ oW1, const float* __restrict__ ob1,
    const float* __restrict__ ogamma, const float* __restrict__ obeta,
    const float* __restrict__ oW2, const float* __restrict__ ob2,
    float* __restrict__ out)
{
    __shared__ float hp[192];
    __shared__ float partial[3];
    const int c = threadIdx.x;
    const int g = blockIdx.x;

    const unsigned u = pooled[g * 192 + c];
    hp[c] = (u == 0u) ? -INFINITY : fdec(u);
    __syncthreads();

    float y = ob1[c];
#pragma unroll 4
    for (int k = 0; k < 192; ++k)
        y += hp[k] * oW1[k * 192 + c];
    y = ogamma[c] * y + obeta[c];
    y = LRELU(y);
    float contrib = y * oW2[c];

#pragma unroll
    for (int off = 32; off > 0; off >>= 1)
        contrib += __shfl_xor(contrib, off);
    if ((threadIdx.x & 63) == 0) partial[threadIdx.x >> 6] = contrib;
    __syncthreads();
    if (threadIdx.x == 0) {
        const float logit = partial[0] + partial[1] + partial[2] + ob2[0];
        out[g] = logit;
        out[128 + g] = 1.0f / (1.0f + expf(-logit));
    }
}

extern "C" void kernel_launch(void* const* d_in, const int* in_sizes, int n_in,
                              void* d_out, int out_size, void* d_ws, size_t ws_size,
                              hipStream_t stream)
{
    const float* x     = (const float*)d_in[0];
    const int*   ei    = (const int*)d_in[1];
    const int*   batch = (const int*)d_in[2];
    const float* eattr = (const float*)d_in[3];
    const float* nW1 = (const float*)d_in[4],  *nb1 = (const float*)d_in[5];
    const float* nW2 = (const float*)d_in[6],  *nb2 = (const float*)d_in[7];
    const float* nW3 = (const float*)d_in[8],  *nb3 = (const float*)d_in[9];
    const float* eW1 = (const float*)d_in[10], *eb1 = (const float*)d_in[11];
    const float* eW2 = (const float*)d_in[12], *eb2 = (const float*)d_in[13];
    const float* eW3 = (const float*)d_in[14], *eb3 = (const float*)d_in[15];
    const float* geps = (const float*)d_in[16];
    const float* gW1 = (const float*)d_in[17], *gb1 = (const float*)d_in[18];
    const float* gW2 = (const float*)d_in[19], *gb2 = (const float*)d_in[20];
    const float* oW1 = (const float*)d_in[21], *ob1 = (const float*)d_in[22];
    const float* ogamma = (const float*)d_in[23], *obeta = (const float*)d_in[24];
    const float* oW2 = (const float*)d_in[25], *ob2 = (const float*)d_in[26];
    float* out = (float*)d_out;

    const int N = in_sizes[0] / 4;   // 100000
    const int E = in_sizes[3] / 8;   // 1600000
    const size_t EP = ((size_t)E + 15) & ~(size_t)15;

    // ---- workspace layout (256B-aligned slices) ----
    char* ws = (char*)d_ws;
    size_t off = 0;
    auto take = [&](size_t bytes) { char* p = ws + off; off += (bytes + 255) & ~(size_t)255; return p; };
    __hip_bfloat16* ea = (__hip_bfloat16*)take(EP * 64 * sizeof(__hip_bfloat16)); // 204.8 MB
    float*    h0     = (float*)take((size_t)N * 64 * sizeof(float));              // 25.6 MB
    float*    h1     = (float*)take((size_t)N * 64 * sizeof(float));              // 25.6 MB
    int*      srcs   = (int*)take((size_t)E * sizeof(int));                       // 6.4 MB
    int*      rowptr = (int*)take(((size_t)N + 1) * sizeof(int));
    unsigned* pooled = (unsigned*)take(128 * 192 * sizeof(unsigned));
    // deg and cursor alias h1 (both dead before any h1 write)
    int* deg    = (int*)h1;
    int* cursor = (int*)((char*)h1 + (((size_t)N * sizeof(int) + 255) & ~(size_t)255));
    (void)ws_size;

    hipMemsetAsync(pooled, 0, 128 * 192 * sizeof(unsigned), stream);
    hipMemsetAsync(deg, 0, (size_t)N * sizeof(int), stream);

    hist_kernel<<<1024, 256, 0, stream>>>(ei, deg, E);
    scan_kernel<<<1, 1024, 0, stream>>>(deg, rowptr, cursor, N);

    node_mlp_kernel<<<512, 256, 0, stream>>>(x, nW1, nb1, nW2, nb2, nW3, nb3, h0, N);
    edge_mlp_mfma<<<1024, 256, 0, stream>>>(eattr, eW1, eb1, eW2, eb2, eW3, eb3,
                                            ei, cursor, srcs, ea, E);

    gine_layer<<<1024, 256, 0, stream>>>(h0, h1, rowptr, srcs, ea, batch, geps,
                                         gW1, gb1, gW2, gb2, pooled, 0, N);
    gine_layer<<<1024, 256, 0, stream>>>(h1, h0, rowptr, srcs, ea, batch, geps,
                                         gW1, gb1, gW2, gb2, pooled, 1, N);
    gine_layer<<<1024, 256, 0, stream>>>(h0, h1, rowptr, srcs, ea, batch, geps,
                                         gW1, gb1, gW2, gb2, pooled, 2, N);

    out_kernel<<<128, 192, 0, stream>>>(pooled, oW1, ob1, ogamma, obeta, oW2, ob2, out);
}

// Round 4
// 958.122 us; speedup vs baseline: 3.7009x; 1.2119x over previous
//
#include <hip/hip_runtime.h>
#include <hip/hip_bf16.h>

#define LRELU(x) ((x) > 0.0f ? (x) : 0.01f * (x))

typedef __attribute__((ext_vector_type(4))) short bf16x4;
typedef __attribute__((ext_vector_type(4))) float f32x4;

// Monotonic float -> uint encoding for max-atomics on pooled.
__device__ __forceinline__ unsigned fenc(float f) {
    unsigned u = __float_as_uint(f);
    return (u & 0x80000000u) ? ~u : (u | 0x80000000u);
}
__device__ __forceinline__ float fdec(unsigned u) {
    return (u & 0x80000000u) ? __uint_as_float(u & 0x7fffffffu) : __uint_as_float(~u);
}
__device__ __forceinline__ short f2bf(float f) {
    unsigned u = __float_as_uint(f);
    unsigned r = (u + 0x7FFFu + ((u >> 16) & 1u)) >> 16;
    return (short)r;
}
__device__ __forceinline__ float bf2f(short s) {
    return __uint_as_float(((unsigned)(unsigned short)s) << 16);
}

__device__ __forceinline__ f32x4 mfma16(bf16x4 a, bf16x4 b, f32x4 c) {
#if __has_builtin(__builtin_amdgcn_mfma_f32_16x16x16bf16_1k)
    return __builtin_amdgcn_mfma_f32_16x16x16bf16_1k(a, b, c, 0, 0, 0);
#else
    asm("v_mfma_f32_16x16x16_bf16 %0, %1, %2, %0" : "+v"(c) : "v"(a), "v"(b));
    return c;
#endif
}

// ---------------------------------------------------------------------------
// CSR build step 1: histogram of dst
// ---------------------------------------------------------------------------
__global__ __launch_bounds__(256) void hist_kernel(const int* __restrict__ ei,
                                                   int* __restrict__ deg, int E)
{
    const int stride = gridDim.x * blockDim.x;
    for (int e = blockIdx.x * blockDim.x + threadIdx.x; e < E; e += stride)
        atomicAdd(&deg[ei[E + e]], 1);
}

// ---------------------------------------------------------------------------
// CSR build step 2: single-block exclusive scan deg -> rowptr (+cursor copy)
// ---------------------------------------------------------------------------
__global__ __launch_bounds__(1024) void scan_kernel(const int* __restrict__ deg,
                                                    int* __restrict__ rowptr,
                                                    int* __restrict__ cursor, int N)
{
    __shared__ int wsum[16];
    __shared__ int tiletot;
    const int lane = threadIdx.x & 63;
    const int w    = threadIdx.x >> 6;
    int carry = 0;
    for (int base = 0; base < N; base += 1024) {
        const int i = base + (int)threadIdx.x;
        const int v = (i < N) ? deg[i] : 0;
        int s = v;
#pragma unroll
        for (int off = 1; off < 64; off <<= 1) {
            int t = __shfl_up(s, off);
            if (lane >= off) s += t;
        }
        if (lane == 63) wsum[w] = s;
        __syncthreads();
        if (threadIdx.x == 0) {
            int acc = 0;
#pragma unroll
            for (int k = 0; k < 16; ++k) { int t = wsum[k]; wsum[k] = acc; acc += t; }
            tiletot = acc;
        }
        __syncthreads();
        const int excl = carry + wsum[w] + (s - v);
        if (i < N) { rowptr[i] = excl; cursor[i] = excl; }
        carry += tiletot;
        __syncthreads();
    }
    if (threadIdx.x == 0) rowptr[N] = carry;
}

// ---------------------------------------------------------------------------
// Edge embedding MLP via MFMA (in-register), fused with CSR scatter:
// each edge's output row (64ch bf16) is written to its dst-sorted position,
// and srcs_sorted[pos] = src. Aggregation then streams ea sequentially.
// D-frag: col(lane&15)=edge, row ch = t*16 + (lane>>4)*4 + j.
// ---------------------------------------------------------------------------
__global__ __launch_bounds__(256) void edge_mlp_mfma(
    const float* __restrict__ eattr,
    const float* __restrict__ W1, const float* __restrict__ b1,
    const float* __restrict__ W2, const float* __restrict__ b2,
    const float* __restrict__ W3, const float* __restrict__ b3,
    const int* __restrict__ ei, int* __restrict__ cursor,
    int* __restrict__ srcs_sorted,
    __hip_bfloat16* __restrict__ eout, int E)
{
    const int lane = threadIdx.x & 63;
    const int el   = lane & 15;   // edge slot
    const int g    = lane >> 4;   // lane group

    bf16x4 w1f[4];
    bf16x4 w2f[4][4];
    bf16x4 w3f[4][4];
    f32x4  bf1[4], bf2[4], bf3[4];
#pragma unroll
    for (int t = 0; t < 4; ++t) {
        const int c = t * 16 + el;
#pragma unroll
        for (int j = 0; j < 4; ++j) {
            const int k = g * 4 + j;
            w1f[t][j] = (k < 8) ? f2bf(W1[k * 64 + c]) : (short)0;
        }
#pragma unroll
        for (int kb = 0; kb < 4; ++kb) {
#pragma unroll
            for (int j = 0; j < 4; ++j) {
                const int k = kb * 16 + g * 4 + j;
                w2f[t][kb][j] = f2bf(W2[k * 64 + c]);
                w3f[t][kb][j] = f2bf(W3[k * 64 + c]);
            }
        }
        const float4 v1 = *reinterpret_cast<const float4*>(b1 + t * 16 + g * 4);
        const float4 v2 = *reinterpret_cast<const float4*>(b2 + t * 16 + g * 4);
        const float4 v3 = *reinterpret_cast<const float4*>(b3 + t * 16 + g * 4);
        bf1[t][0] = v1.x; bf1[t][1] = v1.y; bf1[t][2] = v1.z; bf1[t][3] = v1.w;
        bf2[t][0] = v2.x; bf2[t][1] = v2.y; bf2[t][2] = v2.z; bf2[t][3] = v2.w;
        bf3[t][0] = v3.x; bf3[t][1] = v3.y; bf3[t][2] = v3.z; bf3[t][3] = v3.w;
    }

    const int nblk = (E + 15) >> 4;
    const int wid  = (int)((blockIdx.x * blockDim.x + threadIdx.x) >> 6);
    const int nw   = (int)((gridDim.x * blockDim.x) >> 6);

    for (int eb = wid; eb < nblk; eb += nw) {
        const int e  = eb * 16 + el;
        const int ec = min(e, E - 1);

        // sorted position for this block's 16 edges (lanes 0..15 do the work)
        int p = 0;
        if (lane < 16) {
            const int eL = eb * 16 + lane;
            if (eL < E) {
                const int d = ei[E + eL];
                p = atomicAdd(&cursor[d], 1);
                srcs_sorted[p] = ei[eL];
            }
        }
        const int pd = __shfl(p, el);

        // B1 fragment: edge attrs (K=8 real, rest zero)
        bf16x4 bfr = (bf16x4)0;
        if (g < 2) {
            const float4 av = *reinterpret_cast<const float4*>(eattr + (size_t)ec * 8 + g * 4);
            bfr[0] = f2bf(av.x); bfr[1] = f2bf(av.y);
            bfr[2] = f2bf(av.z); bfr[3] = f2bf(av.w);
        }

        f32x4  acc[4];
        bf16x4 act[4];

#pragma unroll
        for (int t = 0; t < 4; ++t) acc[t] = mfma16(w1f[t], bfr, bf1[t]);
#pragma unroll
        for (int t = 0; t < 4; ++t)
#pragma unroll
            for (int j = 0; j < 4; ++j) act[t][j] = f2bf(fmaxf(acc[t][j], 0.0f));

#pragma unroll
        for (int t = 0; t < 4; ++t) {
            f32x4 a = bf2[t];
#pragma unroll
            for (int kb = 0; kb < 4; ++kb) a = mfma16(w2f[t][kb], act[kb], a);
            acc[t] = a;
        }
#pragma unroll
        for (int t = 0; t < 4; ++t)
#pragma unroll
            for (int j = 0; j < 4; ++j) act[t][j] = f2bf(fmaxf(acc[t][j], 0.0f));

#pragma unroll
        for (int t = 0; t < 4; ++t) {
            f32x4 a = bf3[t];
#pragma unroll
            for (int kb = 0; kb < 4; ++kb) a = mfma16(w3f[t][kb], act[kb], a);
            bf16x4 o;
#pragma unroll
            for (int j = 0; j < 4; ++j) o[j] = f2bf(a[j]);
            if (e < E) {
                // row-major store into dst-sorted row pd: ch = t*16 + g*4 .. +3
                *reinterpret_cast<bf16x4*>(
                    reinterpret_cast<short*>(eout) + (size_t)pd * 64 + t * 16 + g * 4) = o;
            }
        }
    }
}

// ---------------------------------------------------------------------------
// Node embedding MLP: x:[N,4] -> h:[N,64] bf16 (weight-stationary VALU)
// ---------------------------------------------------------------------------
__global__ __launch_bounds__(256) void node_mlp_kernel(
    const float* __restrict__ x,
    const float* __restrict__ W1, const float* __restrict__ b1,
    const float* __restrict__ W2, const float* __restrict__ b2,
    const float* __restrict__ W3, const float* __restrict__ b3,
    __hip_bfloat16* __restrict__ h, int N)
{
    __shared__ __align__(16) float smem[4 * 64];
    const int lane = threadIdx.x & 63;
    const int wid  = threadIdx.x >> 6;

    float w1c[4], w2c[64], w3c[64];
#pragma unroll
    for (int i = 0; i < 4; ++i)  w1c[i] = W1[i * 64 + lane];
#pragma unroll
    for (int k = 0; k < 64; ++k) w2c[k] = W2[k * 64 + lane];
#pragma unroll
    for (int k = 0; k < 64; ++k) w3c[k] = W3[k * 64 + lane];
    const float bb1 = b1[lane], bb2 = b2[lane], bb3 = b3[lane];

    const int nwave = gridDim.x * 4;
    const int w     = blockIdx.x * 4 + wid;
    const int chunk = (N + nwave - 1) / nwave;
    const int n0 = w * chunk;
    const int n1 = min(N, n0 + chunk);
    float* myrow = &smem[wid * 64];
    short* hb = reinterpret_cast<short*>(h);

    for (int n = n0; n < n1; ++n) {
        const float4 xv = *reinterpret_cast<const float4*>(x + (size_t)n * 4);
        float a1 = bb1 + xv.x * w1c[0] + xv.y * w1c[1] + xv.z * w1c[2] + xv.w * w1c[3];
        a1 = fmaxf(a1, 0.0f);
        myrow[lane] = a1;
        asm volatile("s_waitcnt lgkmcnt(0)" ::: "memory");
        float s0 = 0.f, s1 = 0.f, s2 = 0.f, s3 = 0.f;
#pragma unroll
        for (int k4 = 0; k4 < 16; ++k4) {
            const float4 hv = *reinterpret_cast<const float4*>(&myrow[k4 * 4]);
            s0 += hv.x * w2c[k4 * 4];     s1 += hv.y * w2c[k4 * 4 + 1];
            s2 += hv.z * w2c[k4 * 4 + 2]; s3 += hv.w * w2c[k4 * 4 + 3];
        }
        float a2 = fmaxf(bb2 + ((s0 + s1) + (s2 + s3)), 0.0f);
        asm volatile("s_waitcnt lgkmcnt(0)" ::: "memory");
        myrow[lane] = a2;
        asm volatile("s_waitcnt lgkmcnt(0)" ::: "memory");
        s0 = 0.f; s1 = 0.f; s2 = 0.f; s3 = 0.f;
#pragma unroll
        for (int k4 = 0; k4 < 16; ++k4) {
            const float4 hv = *reinterpret_cast<const float4*>(&myrow[k4 * 4]);
            s0 += hv.x * w3c[k4 * 4];     s1 += hv.y * w3c[k4 * 4 + 1];
            s2 += hv.z * w3c[k4 * 4 + 2]; s3 += hv.w * w3c[k4 * 4 + 3];
        }
        hb[(size_t)n * 64 + lane] = f2bf(bb3 + ((s0 + s1) + (s2 + s3)));
    }
}

// ---------------------------------------------------------------------------
// Fused GINE layer: CSR max-aggregation + node MLP + pooling.
// h in/out are bf16. 16 edges in flight via 4x4 unroll with clamp-to-last
// (duplicates are harmless under max). rowptr reused across contiguous nodes.
// ---------------------------------------------------------------------------
__global__ __launch_bounds__(256) void gine_layer(
    const __hip_bfloat16* __restrict__ h_in, __hip_bfloat16* __restrict__ h_out,
    const int* __restrict__ rowptr, const int* __restrict__ srcs,
    const __hip_bfloat16* __restrict__ eas,
    const int* __restrict__ batch, const float* __restrict__ geps,
    const float* __restrict__ gW1, const float* __restrict__ gb1,
    const float* __restrict__ gW2, const float* __restrict__ gb2,
    unsigned* __restrict__ pooled, int l, int N)
{
    __shared__ __align__(16) float smem[4 * 64];
    const int lane = threadIdx.x & 63;
    const int wid  = threadIdx.x >> 6;
    const int g    = lane >> 4;
    const int el   = lane & 15;

    const float* W1 = gW1 + (size_t)l * 4096;
    const float* W2 = gW2 + (size_t)l * 4096;
    float w1c[64], w2c[64];
#pragma unroll
    for (int k = 0; k < 64; ++k) w1c[k] = W1[k * 64 + lane];
#pragma unroll
    for (int k = 0; k < 64; ++k) w2c[k] = W2[k * 64 + lane];
    const float bb1 = gb1[l * 64 + lane], bb2 = gb2[l * 64 + lane];
    const float ope = 1.0f + geps[l];

    const int nwave = gridDim.x * 4;
    const int w     = blockIdx.x * 4 + wid;
    const int chunk = (N + nwave - 1) / nwave;
    const int n0 = w * chunk;
    const int n1 = min(N, n0 + chunk);
    if (n0 >= n1) return;
    float* myrow = &smem[wid * 64];
    const short* hip = reinterpret_cast<const short*>(h_in);
    const short* eap = reinterpret_cast<const short*>(eas);
    short* hop = reinterpret_cast<short*>(h_out);

    int curg = -1;
    float vmax = 0.0f;
    int r0 = rowptr[n0];
    for (int n = n0; n < n1; ++n) {
        const int r1 = rowptr[n + 1];

        float m0 = -INFINITY, m1 = -INFINITY, m2 = -INFINITY, m3 = -INFINITY;
        for (int r = r0; r < r1; r += 16) {
#pragma unroll
            for (int u = 0; u < 4; ++u) {
                const int rc = min(r + u * 4 + g, r1 - 1);
                const int s  = srcs[rc];
                const bf16x4 hv = *reinterpret_cast<const bf16x4*>(hip + (size_t)s * 64 + el * 4);
                const bf16x4 ev = *reinterpret_cast<const bf16x4*>(eap + (size_t)rc * 64 + el * 4);
                float c0 = bf2f(hv[0]) + bf2f(ev[0]);
                float c1 = bf2f(hv[1]) + bf2f(ev[1]);
                float c2 = bf2f(hv[2]) + bf2f(ev[2]);
                float c3 = bf2f(hv[3]) + bf2f(ev[3]);
                c0 = LRELU(c0); c1 = LRELU(c1); c2 = LRELU(c2); c3 = LRELU(c3);
                m0 = fmaxf(m0, c0); m1 = fmaxf(m1, c1);
                m2 = fmaxf(m2, c2); m3 = fmaxf(m3, c3);
            }
        }
        // combine the 4 edge-groups (lanes el, el+16, el+32, el+48)
        m0 = fmaxf(m0, __shfl_xor(m0, 16)); m0 = fmaxf(m0, __shfl_xor(m0, 32));
        m1 = fmaxf(m1, __shfl_xor(m1, 16)); m1 = fmaxf(m1, __shfl_xor(m1, 32));
        m2 = fmaxf(m2, __shfl_xor(m2, 16)); m2 = fmaxf(m2, __shfl_xor(m2, 32));
        m3 = fmaxf(m3, __shfl_xor(m3, 16)); m3 = fmaxf(m3, __shfl_xor(m3, 32));

        const bf16x4 hn = *reinterpret_cast<const bf16x4*>(hip + (size_t)n * 64 + el * 4);
        float4 z;
        z.x = ope * bf2f(hn[0]) + ((m0 == -INFINITY) ? 0.0f : m0);
        z.y = ope * bf2f(hn[1]) + ((m1 == -INFINITY) ? 0.0f : m1);
        z.z = ope * bf2f(hn[2]) + ((m2 == -INFINITY) ? 0.0f : m2);
        z.w = ope * bf2f(hn[3]) + ((m3 == -INFINITY) ? 0.0f : m3);
        if (g == 0) *reinterpret_cast<float4*>(&myrow[el * 4]) = z;
        asm volatile("s_waitcnt lgkmcnt(0)" ::: "memory");

        float s0 = 0.f, s1 = 0.f, s2 = 0.f, s3 = 0.f;
#pragma unroll
        for (int k4 = 0; k4 < 16; ++k4) {
            const float4 zv = *reinterpret_cast<const float4*>(&myrow[k4 * 4]);
            s0 += zv.x * w1c[k4 * 4];     s1 += zv.y * w1c[k4 * 4 + 1];
            s2 += zv.z * w1c[k4 * 4 + 2]; s3 += zv.w * w1c[k4 * 4 + 3];
        }
        float t = bb1 + ((s0 + s1) + (s2 + s3));
        t = LRELU(t);
        asm volatile("s_waitcnt lgkmcnt(0)" ::: "memory");
        myrow[lane] = t;
        asm volatile("s_waitcnt lgkmcnt(0)" ::: "memory");
        s0 = 0.f; s1 = 0.f; s2 = 0.f; s3 = 0.f;
#pragma unroll
        for (int k4 = 0; k4 < 16; ++k4) {
            const float4 tv = *reinterpret_cast<const float4*>(&myrow[k4 * 4]);
            s0 += tv.x * w2c[k4 * 4];     s1 += tv.y * w2c[k4 * 4 + 1];
            s2 += tv.z * w2c[k4 * 4 + 2]; s3 += tv.w * w2c[k4 * 4 + 3];
        }
        const float o = bb2 + ((s0 + s1) + (s2 + s3));
        hop[(size_t)n * 64 + lane] = f2bf(o);

        const int gb = batch[n];  // sorted, wave-uniform
        if (gb != curg) {
            if (curg >= 0)
                atomicMax(&pooled[curg * 192 + l * 64 + lane], fenc(vmax));
            curg = gb;
            vmax = o;
        } else {
            vmax = fmaxf(vmax, o);
        }
        r0 = r1;
    }
    atomicMax(&pooled[curg * 192 + l * 64 + lane], fenc(vmax));
}

// ---------------------------------------------------------------------------
// Output head
// ---------------------------------------------------------------------------
__global__ __launch_bounds__(192) void out_kernel(
    const unsigned* __restrict__ pooled,
    const float* __restrict__ oW1, const float* __restrict__ ob1,
    const float* __restrict__ ogamma, const float* __restrict__ obeta,
    const float* __restrict__ oW2, const float* __restrict__ ob2,
    float* __restrict__ out)
{
    __shared__ float hp[192];
    __shared__ float partial[3];
    const int c = threadIdx.x;
    const int g = blockIdx.x;

    const unsigned u = pooled[g * 192 + c];
    hp[c] = (u == 0u) ? -INFINITY : fdec(u);
    __syncthreads();

    float y = ob1[c];
#pragma unroll 4
    for (int k = 0; k < 192; ++k)
        y += hp[k] * oW1[k * 192 + c];
    y = ogamma[c] * y + obeta[c];
    y = LRELU(y);
    float contrib = y * oW2[c];

#pragma unroll
    for (int off = 32; off > 0; off >>= 1)
        contrib += __shfl_xor(contrib, off);
    if ((threadIdx.x & 63) == 0) partial[threadIdx.x >> 6] = contrib;
    __syncthreads();
    if (threadIdx.x == 0) {
        const float logit = partial[0] + partial[1] + partial[2] + ob2[0];
        out[g] = logit;
        out[128 + g] = 1.0f / (1.0f + expf(-logit));
    }
}

extern "C" void kernel_launch(void* const* d_in, const int* in_sizes, int n_in,
                              void* d_out, int out_size, void* d_ws, size_t ws_size,
                              hipStream_t stream)
{
    const float* x     = (const float*)d_in[0];
    const int*   ei    = (const int*)d_in[1];
    const int*   batch = (const int*)d_in[2];
    const float* eattr = (const float*)d_in[3];
    const float* nW1 = (const float*)d_in[4],  *nb1 = (const float*)d_in[5];
    const float* nW2 = (const float*)d_in[6],  *nb2 = (const float*)d_in[7];
    const float* nW3 = (const float*)d_in[8],  *nb3 = (const float*)d_in[9];
    const float* eW1 = (const float*)d_in[10], *eb1 = (const float*)d_in[11];
    const float* eW2 = (const float*)d_in[12], *eb2 = (const float*)d_in[13];
    const float* eW3 = (const float*)d_in[14], *eb3 = (const float*)d_in[15];
    const float* geps = (const float*)d_in[16];
    const float* gW1 = (const float*)d_in[17], *gb1 = (const float*)d_in[18];
    const float* gW2 = (const float*)d_in[19], *gb2 = (const float*)d_in[20];
    const float* oW1 = (const float*)d_in[21], *ob1 = (const float*)d_in[22];
    const float* ogamma = (const float*)d_in[23], *obeta = (const float*)d_in[24];
    const float* oW2 = (const float*)d_in[25], *ob2 = (const float*)d_in[26];
    float* out = (float*)d_out;

    const int N = in_sizes[0] / 4;   // 100000
    const int E = in_sizes[3] / 8;   // 1600000
    const size_t EP = ((size_t)E + 15) & ~(size_t)15;

    // ---- workspace layout (256B-aligned slices) ----
    char* ws = (char*)d_ws;
    size_t off = 0;
    auto take = [&](size_t bytes) { char* p = ws + off; off += (bytes + 255) & ~(size_t)255; return p; };
    __hip_bfloat16* ea = (__hip_bfloat16*)take(EP * 64 * sizeof(__hip_bfloat16)); // 204.8 MB
    __hip_bfloat16* h0 = (__hip_bfloat16*)take((size_t)N * 64 * sizeof(__hip_bfloat16)); // 12.8 MB
    __hip_bfloat16* h1 = (__hip_bfloat16*)take((size_t)N * 64 * sizeof(__hip_bfloat16)); // 12.8 MB
    int*      srcs   = (int*)take((size_t)E * sizeof(int));                       // 6.4 MB
    int*      rowptr = (int*)take(((size_t)N + 1) * sizeof(int));
    unsigned* pooled = (unsigned*)take(128 * 192 * sizeof(unsigned));
    // deg and cursor alias h1 (both dead before any h1 write)
    int* deg    = (int*)h1;
    int* cursor = (int*)((char*)h1 + (((size_t)N * sizeof(int) + 255) & ~(size_t)255));
    (void)ws_size;

    hipMemsetAsync(pooled, 0, 128 * 192 * sizeof(unsigned), stream);
    hipMemsetAsync(deg, 0, (size_t)N * sizeof(int), stream);

    hist_kernel<<<2048, 256, 0, stream>>>(ei, deg, E);
    scan_kernel<<<1, 1024, 0, stream>>>(deg, rowptr, cursor, N);

    node_mlp_kernel<<<512, 256, 0, stream>>>(x, nW1, nb1, nW2, nb2, nW3, nb3, h0, N);
    edge_mlp_mfma<<<2048, 256, 0, stream>>>(eattr, eW1, eb1, eW2, eb2, eW3, eb3,
                                            ei, cursor, srcs, ea, E);

    gine_layer<<<2048, 256, 0, stream>>>(h0, h1, rowptr, srcs, ea, batch, geps,
                                         gW1, gb1, gW2, gb2, pooled, 0, N);
    gine_layer<<<2048, 256, 0, stream>>>(h1, h0, rowptr, srcs, ea, batch, geps,
                                         gW1, gb1, gW2, gb2, pooled, 1, N);
    gine_layer<<<2048, 256, 0, stream>>>(h0, h1, rowptr, srcs, ea, batch, geps,
                                         gW1, gb1, gW2, gb2, pooled, 2, N);

    out_kernel<<<128, 192, 0, stream>>>(pooled, oW1, ob1, ogamma, obeta, oW2, ob2, out);
}

// Round 5
// 725.162 us; speedup vs baseline: 4.8899x; 1.3213x over previous
//
#include <hip/hip_runtime.h>
#include <hip/hip_bf16.h>

#define LRELU(x) ((x) > 0.0f ? (x) : 0.01f * (x))

typedef __attribute__((ext_vector_type(4))) short bf16x4;
typedef __attribute__((ext_vector_type(8))) short bf16x8;
typedef __attribute__((ext_vector_type(4))) float f32x4;

// Monotonic float -> uint encoding for max-atomics on pooled.
__device__ __forceinline__ unsigned fenc(float f) {
    unsigned u = __float_as_uint(f);
    return (u & 0x80000000u) ? ~u : (u | 0x80000000u);
}
__device__ __forceinline__ float fdec(unsigned u) {
    return (u & 0x80000000u) ? __uint_as_float(u & 0x7fffffffu) : __uint_as_float(~u);
}
__device__ __forceinline__ short f2bf(float f) {
    unsigned u = __float_as_uint(f);
    unsigned r = (u + 0x7FFFu + ((u >> 16) & 1u)) >> 16;
    return (short)r;
}
__device__ __forceinline__ float bf2f(short s) {
    return __uint_as_float(((unsigned)(unsigned short)s) << 16);
}

__device__ __forceinline__ f32x4 mfma16(bf16x4 a, bf16x4 b, f32x4 c) {
#if __has_builtin(__builtin_amdgcn_mfma_f32_16x16x16bf16_1k)
    return __builtin_amdgcn_mfma_f32_16x16x16bf16_1k(a, b, c, 0, 0, 0);
#else
    asm("v_mfma_f32_16x16x16_bf16 %0, %1, %2, %0" : "+v"(c) : "v"(a), "v"(b));
    return c;
#endif
}

// ---------------------------------------------------------------------------
// CSR build step 1: histogram of dst
// ---------------------------------------------------------------------------
__global__ __launch_bounds__(256) void hist_kernel(const int* __restrict__ ei,
                                                   int* __restrict__ deg, int E)
{
    const int stride = gridDim.x * blockDim.x;
    for (int e = blockIdx.x * blockDim.x + threadIdx.x; e < E; e += stride)
        atomicAdd(&deg[ei[E + e]], 1);
}

// ---------------------------------------------------------------------------
// CSR build step 2: single-block exclusive scan (4 elems/thread per tile)
// ---------------------------------------------------------------------------
__global__ __launch_bounds__(1024) void scan_kernel(const int* __restrict__ deg,
                                                    int* __restrict__ rowptr,
                                                    int* __restrict__ cursor, int N)
{
    __shared__ int wsum[16];
    __shared__ int tiletot;
    const int lane = threadIdx.x & 63;
    const int w    = threadIdx.x >> 6;
    int carry = 0;
    for (int base = 0; base < N; base += 4096) {
        const int i = base + (int)threadIdx.x * 4;
        int4 v = {0, 0, 0, 0};
        if (i + 3 < N) {
            v = *reinterpret_cast<const int4*>(deg + i);
        } else {
            if (i < N)     v.x = deg[i];
            if (i + 1 < N) v.y = deg[i + 1];
            if (i + 2 < N) v.z = deg[i + 2];
        }
        const int tot = v.x + v.y + v.z + v.w;
        int s = tot;
#pragma unroll
        for (int off = 1; off < 64; off <<= 1) {
            int t = __shfl_up(s, off);
            if (lane >= off) s += t;
        }
        if (lane == 63) wsum[w] = s;
        __syncthreads();
        if (threadIdx.x == 0) {
            int acc = 0;
#pragma unroll
            for (int k = 0; k < 16; ++k) { int t = wsum[k]; wsum[k] = acc; acc += t; }
            tiletot = acc;
        }
        __syncthreads();
        const int excl = carry + wsum[w] + (s - tot);
        int4 o;
        o.x = excl; o.y = excl + v.x; o.z = o.y + v.y; o.w = o.z + v.z;
        if (i + 3 < N) {
            *reinterpret_cast<int4*>(rowptr + i) = o;
            *reinterpret_cast<int4*>(cursor + i) = o;
        } else {
            if (i < N)     { rowptr[i] = o.x;     cursor[i] = o.x; }
            if (i + 1 < N) { rowptr[i + 1] = o.y; cursor[i + 1] = o.y; }
            if (i + 2 < N) { rowptr[i + 2] = o.z; cursor[i + 2] = o.z; }
        }
        carry += tiletot;
        __syncthreads();
    }
    if (threadIdx.x == 0) rowptr[N] = carry;
}

// ---------------------------------------------------------------------------
// Scatter edge_attr (as bf16, 16B) + src (4B) into dst-sorted order.
// Converts the 128B/edge write-scatter of ea into a 20B/edge input scatter.
// ---------------------------------------------------------------------------
__global__ __launch_bounds__(256) void scatter_kernel(
    const int* __restrict__ ei, const float* __restrict__ eattr,
    int* __restrict__ cursor, int* __restrict__ src_s,
    short* __restrict__ eattr_s, int E)
{
    const int stride = gridDim.x * blockDim.x;
    for (int e = blockIdx.x * blockDim.x + threadIdx.x; e < E; e += stride) {
        const int d = ei[E + e];
        const int p = atomicAdd(&cursor[d], 1);
        src_s[p] = ei[e];
        const float4 a0 = *reinterpret_cast<const float4*>(eattr + (size_t)e * 8);
        const float4 a1 = *reinterpret_cast<const float4*>(eattr + (size_t)e * 8 + 4);
        bf16x8 o;
        o[0] = f2bf(a0.x); o[1] = f2bf(a0.y); o[2] = f2bf(a0.z); o[3] = f2bf(a0.w);
        o[4] = f2bf(a1.x); o[5] = f2bf(a1.y); o[6] = f2bf(a1.z); o[7] = f2bf(a1.w);
        *reinterpret_cast<bf16x8*>(eattr_s + (size_t)p * 8) = o;
    }
}

// ---------------------------------------------------------------------------
// Edge embedding MLP via MFMA, fully coalesced: reads dst-sorted bf16 attrs,
// writes ea rows at the SAME (sorted) index -> contiguous full-line stores.
// D-frag: col(lane&15)=edge slot, row ch = t*16 + (lane>>4)*4 + j.
// ---------------------------------------------------------------------------
__global__ __launch_bounds__(256) void edge_mlp_mfma(
    const short* __restrict__ eattr_s,
    const float* __restrict__ W1, const float* __restrict__ b1,
    const float* __restrict__ W2, const float* __restrict__ b2,
    const float* __restrict__ W3, const float* __restrict__ b3,
    short* __restrict__ eout, int E)
{
    const int lane = threadIdx.x & 63;
    const int el   = lane & 15;
    const int g    = lane >> 4;

    bf16x4 w1f[4];
    bf16x4 w2f[4][4];
    bf16x4 w3f[4][4];
    f32x4  bf1[4], bf2[4], bf3[4];
#pragma unroll
    for (int t = 0; t < 4; ++t) {
        const int c = t * 16 + el;
#pragma unroll
        for (int j = 0; j < 4; ++j) {
            const int k = g * 4 + j;
            w1f[t][j] = (k < 8) ? f2bf(W1[k * 64 + c]) : (short)0;
        }
#pragma unroll
        for (int kb = 0; kb < 4; ++kb) {
#pragma unroll
            for (int j = 0; j < 4; ++j) {
                const int k = kb * 16 + g * 4 + j;
                w2f[t][kb][j] = f2bf(W2[k * 64 + c]);
                w3f[t][kb][j] = f2bf(W3[k * 64 + c]);
            }
        }
        const float4 v1 = *reinterpret_cast<const float4*>(b1 + t * 16 + g * 4);
        const float4 v2 = *reinterpret_cast<const float4*>(b2 + t * 16 + g * 4);
        const float4 v3 = *reinterpret_cast<const float4*>(b3 + t * 16 + g * 4);
        bf1[t][0] = v1.x; bf1[t][1] = v1.y; bf1[t][2] = v1.z; bf1[t][3] = v1.w;
        bf2[t][0] = v2.x; bf2[t][1] = v2.y; bf2[t][2] = v2.z; bf2[t][3] = v2.w;
        bf3[t][0] = v3.x; bf3[t][1] = v3.y; bf3[t][2] = v3.z; bf3[t][3] = v3.w;
    }

    const int nblk = (E + 15) >> 4;
    const int wid  = (int)((blockIdx.x * blockDim.x + threadIdx.x) >> 6);
    const int nw   = (int)((gridDim.x * blockDim.x) >> 6);

    for (int eb = wid; eb < nblk; eb += nw) {
        const int e  = eb * 16 + el;
        const int ec = min(e, E - 1);

        bf16x4 bfr = (bf16x4)0;
        if (g < 2)
            bfr = *reinterpret_cast<const bf16x4*>(eattr_s + (size_t)ec * 8 + g * 4);

        f32x4  acc[4];
        bf16x4 act[4];

#pragma unroll
        for (int t = 0; t < 4; ++t) acc[t] = mfma16(w1f[t], bfr, bf1[t]);
#pragma unroll
        for (int t = 0; t < 4; ++t)
#pragma unroll
            for (int j = 0; j < 4; ++j) act[t][j] = f2bf(fmaxf(acc[t][j], 0.0f));

#pragma unroll
        for (int t = 0; t < 4; ++t) {
            f32x4 a = bf2[t];
#pragma unroll
            for (int kb = 0; kb < 4; ++kb) a = mfma16(w2f[t][kb], act[kb], a);
            acc[t] = a;
        }
#pragma unroll
        for (int t = 0; t < 4; ++t)
#pragma unroll
            for (int j = 0; j < 4; ++j) act[t][j] = f2bf(fmaxf(acc[t][j], 0.0f));

#pragma unroll
        for (int t = 0; t < 4; ++t) {
            f32x4 a = bf3[t];
#pragma unroll
            for (int kb = 0; kb < 4; ++kb) a = mfma16(w3f[t][kb], act[kb], a);
            bf16x4 o;
#pragma unroll
            for (int j = 0; j < 4; ++j) o[j] = f2bf(a[j]);
            if (e < E)
                *reinterpret_cast<bf16x4*>(eout + (size_t)e * 64 + t * 16 + g * 4) = o;
        }
    }
}

// ---------------------------------------------------------------------------
// Node embedding MLP: x:[N,4] -> h:[N,64] bf16 (weight-stationary VALU)
// ---------------------------------------------------------------------------
__global__ __launch_bounds__(256) void node_mlp_kernel(
    const float* __restrict__ x,
    const float* __restrict__ W1, const float* __restrict__ b1,
    const float* __restrict__ W2, const float* __restrict__ b2,
    const float* __restrict__ W3, const float* __restrict__ b3,
    short* __restrict__ h, int N)
{
    __shared__ __align__(16) float smem[4 * 64];
    const int lane = threadIdx.x & 63;
    const int wid  = threadIdx.x >> 6;

    float w1c[4], w2c[64], w3c[64];
#pragma unroll
    for (int i = 0; i < 4; ++i)  w1c[i] = W1[i * 64 + lane];
#pragma unroll
    for (int k = 0; k < 64; ++k) w2c[k] = W2[k * 64 + lane];
#pragma unroll
    for (int k = 0; k < 64; ++k) w3c[k] = W3[k * 64 + lane];
    const float bb1 = b1[lane], bb2 = b2[lane], bb3 = b3[lane];

    const int nwave = gridDim.x * 4;
    const int w     = blockIdx.x * 4 + wid;
    const int chunk = (N + nwave - 1) / nwave;
    const int n0 = w * chunk;
    const int n1 = min(N, n0 + chunk);
    float* myrow = &smem[wid * 64];

    for (int n = n0; n < n1; ++n) {
        const float4 xv = *reinterpret_cast<const float4*>(x + (size_t)n * 4);
        float a1 = bb1 + xv.x * w1c[0] + xv.y * w1c[1] + xv.z * w1c[2] + xv.w * w1c[3];
        a1 = fmaxf(a1, 0.0f);
        myrow[lane] = a1;
        asm volatile("s_waitcnt lgkmcnt(0)" ::: "memory");
        float s0 = 0.f, s1 = 0.f, s2 = 0.f, s3 = 0.f;
#pragma unroll
        for (int k4 = 0; k4 < 16; ++k4) {
            const float4 hv = *reinterpret_cast<const float4*>(&myrow[k4 * 4]);
            s0 += hv.x * w2c[k4 * 4];     s1 += hv.y * w2c[k4 * 4 + 1];
            s2 += hv.z * w2c[k4 * 4 + 2]; s3 += hv.w * w2c[k4 * 4 + 3];
        }
        float a2 = fmaxf(bb2 + ((s0 + s1) + (s2 + s3)), 0.0f);
        asm volatile("s_waitcnt lgkmcnt(0)" ::: "memory");
        myrow[lane] = a2;
        asm volatile("s_waitcnt lgkmcnt(0)" ::: "memory");
        s0 = 0.f; s1 = 0.f; s2 = 0.f; s3 = 0.f;
#pragma unroll
        for (int k4 = 0; k4 < 16; ++k4) {
            const float4 hv = *reinterpret_cast<const float4*>(&myrow[k4 * 4]);
            s0 += hv.x * w3c[k4 * 4];     s1 += hv.y * w3c[k4 * 4 + 1];
            s2 += hv.z * w3c[k4 * 4 + 2]; s3 += hv.w * w3c[k4 * 4 + 3];
        }
        h[(size_t)n * 64 + lane] = f2bf(bb3 + ((s0 + s1) + (s2 + s3)));
    }
}

// ---------------------------------------------------------------------------
// Aggregation only: z = (1+eps)*h + segment_max(leaky(h[src]+ea)) as bf16.
// No stationary weights -> low VGPR -> high occupancy for gather latency.
// 16 edges in flight (clamp-to-last; duplicates harmless under max).
// ---------------------------------------------------------------------------
__global__ __launch_bounds__(256) void agg_kernel(
    const short* __restrict__ h_in, short* __restrict__ z_out,
    const int* __restrict__ rowptr, const int* __restrict__ srcs,
    const short* __restrict__ ea,
    const float* __restrict__ geps, int l, int N)
{
    const int lane = threadIdx.x & 63;
    const int g    = lane >> 4;
    const int el   = lane & 15;
    const float ope = 1.0f + geps[l];

    const int nwave = gridDim.x * 4;
    const int w     = blockIdx.x * 4 + (threadIdx.x >> 6);
    const int chunk = (N + nwave - 1) / nwave;
    const int n0 = w * chunk;
    const int n1 = min(N, n0 + chunk);
    if (n0 >= n1) return;

    int r0 = rowptr[n0];
    for (int n = n0; n < n1; ++n) {
        const int r1 = rowptr[n + 1];

        float m0 = -INFINITY, m1 = -INFINITY, m2 = -INFINITY, m3 = -INFINITY;
        for (int r = r0; r < r1; r += 16) {
#pragma unroll
            for (int u = 0; u < 4; ++u) {
                const int rc = min(r + u * 4 + g, r1 - 1);
                const int s  = srcs[rc];
                const bf16x4 hv = *reinterpret_cast<const bf16x4*>(h_in + (size_t)s * 64 + el * 4);
                const bf16x4 ev = *reinterpret_cast<const bf16x4*>(ea + (size_t)rc * 64 + el * 4);
                float c0 = bf2f(hv[0]) + bf2f(ev[0]);
                float c1 = bf2f(hv[1]) + bf2f(ev[1]);
                float c2 = bf2f(hv[2]) + bf2f(ev[2]);
                float c3 = bf2f(hv[3]) + bf2f(ev[3]);
                c0 = LRELU(c0); c1 = LRELU(c1); c2 = LRELU(c2); c3 = LRELU(c3);
                m0 = fmaxf(m0, c0); m1 = fmaxf(m1, c1);
                m2 = fmaxf(m2, c2); m3 = fmaxf(m3, c3);
            }
        }
        m0 = fmaxf(m0, __shfl_xor(m0, 16)); m0 = fmaxf(m0, __shfl_xor(m0, 32));
        m1 = fmaxf(m1, __shfl_xor(m1, 16)); m1 = fmaxf(m1, __shfl_xor(m1, 32));
        m2 = fmaxf(m2, __shfl_xor(m2, 16)); m2 = fmaxf(m2, __shfl_xor(m2, 32));
        m3 = fmaxf(m3, __shfl_xor(m3, 16)); m3 = fmaxf(m3, __shfl_xor(m3, 32));

        if (g == 0) {
            const bf16x4 hn = *reinterpret_cast<const bf16x4*>(h_in + (size_t)n * 64 + el * 4);
            bf16x4 zo;
            zo[0] = f2bf(ope * bf2f(hn[0]) + ((m0 == -INFINITY) ? 0.0f : m0));
            zo[1] = f2bf(ope * bf2f(hn[1]) + ((m1 == -INFINITY) ? 0.0f : m1));
            zo[2] = f2bf(ope * bf2f(hn[2]) + ((m2 == -INFINITY) ? 0.0f : m2));
            zo[3] = f2bf(ope * bf2f(hn[3]) + ((m3 == -INFINITY) ? 0.0f : m3));
            *reinterpret_cast<bf16x4*>(z_out + (size_t)n * 64 + el * 4) = zo;
        }
        r0 = r1;
    }
}

// ---------------------------------------------------------------------------
// GINE node MLP via MFMA (16 nodes/wave-iter) + graph pooling.
// B-frag loads straight from row-major bf16 z; D-frag stores to row-major h.
// Pooling: 4-step shfl_xor max over node lanes, 1 atomic round per block
// (fallback to per-node atomics for blocks spanning a graph boundary).
// ---------------------------------------------------------------------------
__global__ __launch_bounds__(256) void mlp_pool_kernel(
    const short* __restrict__ z, short* __restrict__ h_out,
    const int* __restrict__ batch,
    const float* __restrict__ gW1, const float* __restrict__ gb1,
    const float* __restrict__ gW2, const float* __restrict__ gb2,
    unsigned* __restrict__ pooled, int l, int N)
{
    const int lane = threadIdx.x & 63;
    const int el   = lane & 15;
    const int g    = lane >> 4;

    const float* W1 = gW1 + (size_t)l * 4096;
    const float* W2 = gW2 + (size_t)l * 4096;
    bf16x4 w1f[4][4], w2f[4][4];
    f32x4  bA[4], bB[4];
#pragma unroll
    for (int t = 0; t < 4; ++t) {
        const int c = t * 16 + el;
#pragma unroll
        for (int kb = 0; kb < 4; ++kb) {
#pragma unroll
            for (int j = 0; j < 4; ++j) {
                const int k = kb * 16 + g * 4 + j;
                w1f[t][kb][j] = f2bf(W1[k * 64 + c]);
                w2f[t][kb][j] = f2bf(W2[k * 64 + c]);
            }
        }
        const float4 v1 = *reinterpret_cast<const float4*>(gb1 + l * 64 + t * 16 + g * 4);
        const float4 v2 = *reinterpret_cast<const float4*>(gb2 + l * 64 + t * 16 + g * 4);
        bA[t][0] = v1.x; bA[t][1] = v1.y; bA[t][2] = v1.z; bA[t][3] = v1.w;
        bB[t][0] = v2.x; bB[t][1] = v2.y; bB[t][2] = v2.z; bB[t][3] = v2.w;
    }

    const int nblk = (N + 15) >> 4;
    const int wid  = (int)((blockIdx.x * blockDim.x + threadIdx.x) >> 6);
    const int nw   = (int)((gridDim.x * blockDim.x) >> 6);

    for (int nb = wid; nb < nblk; nb += nw) {
        const int n  = nb * 16 + el;
        const bool valid = (n < N);
        const int nc = valid ? n : (N - 1);

        bf16x4 zf[4];
#pragma unroll
        for (int kb = 0; kb < 4; ++kb)
            zf[kb] = *reinterpret_cast<const bf16x4*>(z + (size_t)nc * 64 + kb * 16 + g * 4);

        f32x4  acc[4];
        bf16x4 act[4];
#pragma unroll
        for (int t = 0; t < 4; ++t) {
            f32x4 a = bA[t];
#pragma unroll
            for (int kb = 0; kb < 4; ++kb) a = mfma16(w1f[t][kb], zf[kb], a);
            acc[t] = a;
        }
#pragma unroll
        for (int t = 0; t < 4; ++t)
#pragma unroll
            for (int j = 0; j < 4; ++j) act[t][j] = f2bf(LRELU(acc[t][j]));

#pragma unroll
        for (int t = 0; t < 4; ++t) {
            f32x4 a = bB[t];
#pragma unroll
            for (int kb = 0; kb < 4; ++kb) a = mfma16(w2f[t][kb], act[kb], a);
            acc[t] = a;
        }

#pragma unroll
        for (int t = 0; t < 4; ++t) {
            bf16x4 o;
#pragma unroll
            for (int j = 0; j < 4; ++j) o[j] = f2bf(acc[t][j]);
            if (valid)
                *reinterpret_cast<bf16x4*>(h_out + (size_t)n * 64 + t * 16 + g * 4) = o;
        }

        // ---- pooling ----
        const int gbl = batch[nc];
        const int gb_first = __shfl(gbl, 0);
        const int gb_last  = __shfl(gbl, 15);
        if (gb_first == gb_last) {
#pragma unroll
            for (int t = 0; t < 4; ++t) {
#pragma unroll
                for (int j = 0; j < 4; ++j) {
                    float v = valid ? acc[t][j] : -INFINITY;
                    v = fmaxf(v, __shfl_xor(v, 1));
                    v = fmaxf(v, __shfl_xor(v, 2));
                    v = fmaxf(v, __shfl_xor(v, 4));
                    v = fmaxf(v, __shfl_xor(v, 8));
                    if (el == 0)
                        atomicMax(&pooled[gb_first * 192 + l * 64 + t * 16 + g * 4 + j], fenc(v));
                }
            }
        } else if (valid) {
#pragma unroll
            for (int t = 0; t < 4; ++t)
#pragma unroll
                for (int j = 0; j < 4; ++j)
                    atomicMax(&pooled[gbl * 192 + l * 64 + t * 16 + g * 4 + j], fenc(acc[t][j]));
        }
    }
}

// ---------------------------------------------------------------------------
// Output head
// ---------------------------------------------------------------------------
__global__ __launch_bounds__(192) void out_kernel(
    const unsigned* __restrict__ pooled,
    const float* __restrict__ oW1, const float* __restrict__ ob1,
    const float* __restrict__ ogamma, const float* __restrict__ obeta,
    const float* __restrict__ oW2, const float* __restrict__ ob2,
    float* __restrict__ out)
{
    __shared__ float hp[192];
    __shared__ float partial[3];
    const int c = threadIdx.x;
    const int g = blockIdx.x;

    const unsigned u = pooled[g * 192 + c];
    hp[c] = (u == 0u) ? -INFINITY : fdec(u);
    __syncthreads();

    float y = ob1[c];
#pragma unroll 4
    for (int k = 0; k < 192; ++k)
        y += hp[k] * oW1[k * 192 + c];
    y = ogamma[c] * y + obeta[c];
    y = LRELU(y);
    float contrib = y * oW2[c];

#pragma unroll
    for (int off = 32; off > 0; off >>= 1)
        contrib += __shfl_xor(contrib, off);
    if ((threadIdx.x & 63) == 0) partial[threadIdx.x >> 6] = contrib;
    __syncthreads();
    if (threadIdx.x == 0) {
        const float logit = partial[0] + partial[1] + partial[2] + ob2[0];
        out[g] = logit;
        out[128 + g] = 1.0f / (1.0f + expf(-logit));
    }
}

extern "C" void kernel_launch(void* const* d_in, const int* in_sizes, int n_in,
                              void* d_out, int out_size, void* d_ws, size_t ws_size,
                              hipStream_t stream)
{
    const float* x     = (const float*)d_in[0];
    const int*   ei    = (const int*)d_in[1];
    const int*   batch = (const int*)d_in[2];
    const float* eattr = (const float*)d_in[3];
    const float* nW1 = (const float*)d_in[4],  *nb1 = (const float*)d_in[5];
    const float* nW2 = (const float*)d_in[6],  *nb2 = (const float*)d_in[7];
    const float* nW3 = (const float*)d_in[8],  *nb3 = (const float*)d_in[9];
    const float* eW1 = (const float*)d_in[10], *eb1 = (const float*)d_in[11];
    const float* eW2 = (const float*)d_in[12], *eb2 = (const float*)d_in[13];
    const float* eW3 = (const float*)d_in[14], *eb3 = (const float*)d_in[15];
    const float* geps = (const float*)d_in[16];
    const float* gW1 = (const float*)d_in[17], *gb1 = (const float*)d_in[18];
    const float* gW2 = (const float*)d_in[19], *gb2 = (const float*)d_in[20];
    const float* oW1 = (const float*)d_in[21], *ob1 = (const float*)d_in[22];
    const float* ogamma = (const float*)d_in[23], *obeta = (const float*)d_in[24];
    const float* oW2 = (const float*)d_in[25], *ob2 = (const float*)d_in[26];
    float* out = (float*)d_out;

    const int N = in_sizes[0] / 4;   // 100000
    const int E = in_sizes[3] / 8;   // 1600000
    const size_t EP = ((size_t)E + 15) & ~(size_t)15;

    // ---- workspace layout (256B-aligned slices) ----
    char* ws = (char*)d_ws;
    size_t off = 0;
    auto take = [&](size_t bytes) { char* p = ws + off; off += (bytes + 255) & ~(size_t)255; return p; };
    short*    ea     = (short*)take(EP * 64 * sizeof(short));            // 204.8 MB
    short*    h0     = (short*)take((size_t)N * 64 * sizeof(short));     // 12.8 MB
    short*    h1     = (short*)take((size_t)N * 64 * sizeof(short));     // 12.8 MB
    int*      srcs   = (int*)take((size_t)E * sizeof(int));              // 6.4 MB
    short*    eattr_s= (short*)take((size_t)EP * 8 * sizeof(short));     // 25.6 MB
    int*      rowptr = (int*)take(((size_t)N + 1) * sizeof(int));
    unsigned* pooled = (unsigned*)take(128 * 192 * sizeof(unsigned));
    // z aliases eattr_s (dead after edge_mlp); deg/cursor alias h1 (dead
    // until mlp_pool layer 0 writes it, after scatter's last cursor use).
    short* zbuf  = eattr_s;
    int* deg    = (int*)h1;
    int* cursor = (int*)((char*)h1 + (((size_t)N * sizeof(int) + 255) & ~(size_t)255));
    (void)ws_size;

    hipMemsetAsync(pooled, 0, 128 * 192 * sizeof(unsigned), stream);
    hipMemsetAsync(deg, 0, (size_t)N * sizeof(int), stream);

    hist_kernel<<<2048, 256, 0, stream>>>(ei, deg, E);
    scan_kernel<<<1, 1024, 0, stream>>>(deg, rowptr, cursor, N);
    node_mlp_kernel<<<512, 256, 0, stream>>>(x, nW1, nb1, nW2, nb2, nW3, nb3, h0, N);
    scatter_kernel<<<2048, 256, 0, stream>>>(ei, eattr, cursor, srcs, eattr_s, E);
    edge_mlp_mfma<<<2048, 256, 0, stream>>>(eattr_s, eW1, eb1, eW2, eb2, eW3, eb3, ea, E);

    for (int l = 0; l < 3; ++l) {
        const short* hi = (l & 1) ? h1 : h0;
        short*       ho = (l & 1) ? h0 : h1;
        agg_kernel<<<2048, 256, 0, stream>>>(hi, zbuf, rowptr, srcs, ea, geps, l, N);
        mlp_pool_kernel<<<1024, 256, 0, stream>>>(zbuf, ho, batch,
                                                  gW1, gb1, gW2, gb2, pooled, l, N);
    }

    out_kernel<<<128, 192, 0, stream>>>(pooled, oW1, ob1, ogamma, obeta, oW2, ob2, out);
}